// Round 3
// baseline (2016.452 us; speedup 1.0000x reference)
//
#include <hip/hip_runtime.h>
#include <hip/hip_bf16.h>

#define B_ 32
#define N_ 2048
#define D_ 16
#define J_ 64
#define C_ 32
#define NCHUNK 32
#define ICHUNK 64          // N_/NCHUNK
#define IPW    16          // ICHUNK/4 waves
#define NPASS  5

typedef __attribute__((ext_vector_type(8)))  short short8;
typedef __attribute__((ext_vector_type(4)))  short s16x4;
typedef __attribute__((ext_vector_type(16))) float f32x16;
typedef __attribute__((ext_vector_type(4)))  float f32x4;

using bf16_t = __hip_bfloat16;

// ---------------------------------------------------------------------------
// Prep: u (B,N,D) fp32 -> u_t (N,B,D) bf16, write-coalesced. Also zeroes the
// per-(pass,j) atomic counters used by the fused combine epilogue.
// ---------------------------------------------------------------------------
__global__ __launch_bounds__(256) void prep_u_kernel(const float* __restrict__ x,
                                                     bf16_t* __restrict__ ut,
                                                     unsigned* __restrict__ counters) {
  int t  = blockIdx.x * 256 + threadIdx.x;   // t = (i*32 + b)*4 + d4
  if (t < NPASS * J_) counters[t] = 0u;
  int d4 = t & 3;
  int bi = t >> 2;
  int b  = bi & 31;
  int i  = bi >> 5;
  f32x4 xv = *(const f32x4*)(x + ((size_t)(b * N_ + i) * D_ + d4 * 4));
  union { s16x4 v; bf16_t h[4]; } o;
  o.h[0] = __float2bfloat16(xv.x);
  o.h[1] = __float2bfloat16(xv.y);
  o.h[2] = __float2bfloat16(xv.z);
  o.h[3] = __float2bfloat16(xv.w);
  *(s16x4*)(ut + (size_t)(i * B_ + b) * D_ + d4 * 4) = o.v;
}

// ---------------------------------------------------------------------------
// Routing pass with FUSED combine epilogue (last-block-per-j pattern).
// One block = (j, i-chunk of 64), 4 waves, 1 wave = 16 i's.
// mfma(wfrag, ufrag) -> acc[m=c][n=b]: col b = lane&31,
// row c = (r&3) + 4*(lane>>5) + 8*(r>>2)   (measured m74/m101)
// Logit dot over c is in-lane (16 fma) + one shfl_xor(32); 1 exp/lane/i.
// MODE 0: fp32 W in (nontemporal), store bf16 W, uniform weights (iter 0)
// MODE 1: bf16 W in, V-based logits (iters 1-4)
// MODE 2/3: fp32-W fallbacks (small ws), uniform / V-logits.
// ---------------------------------------------------------------------------
template<int MODE>
__global__ __launch_bounds__(256) void pass_kernel(
    const float*  __restrict__ Wf,
    const bf16_t* __restrict__ Wb,
    bf16_t*       __restrict__ Wbo,
    const bf16_t* __restrict__ ut,
    const float*  __restrict__ V,
    float*        __restrict__ PS,
    float*        __restrict__ PZ,
    float*        __restrict__ Vout,
    float*        __restrict__ out,
    unsigned*     __restrict__ counter,
    int first, int last)
{
  constexpr bool UNIFORM = (MODE == 0 || MODE == 2);
  constexpr bool READF32 = (MODE != 1);
  constexpr bool STOREB  = (MODE == 0);

  const int tid  = threadIdx.x;
  const int w    = tid >> 6;
  const int lane = tid & 63;
  const int half = lane >> 5;
  const int lc   = lane & 31;          // = b (acc col); A/B-frag free index

  const int j  = blockIdx.x / NCHUNK;
  const int ch = blockIdx.x % NCHUNK;

  int crow[16];                        // acc row (= c) per accumulator reg
#pragma unroll
  for (int r = 0; r < 16; ++r) crow[r] = (r & 3) + 4 * half + 8 * (r >> 2);

  float Vreg[16];
  if (!UNIFORM) {
#pragma unroll
    for (int r = 0; r < 16; ++r) Vreg[r] = V[(lc * J_ + j) * C_ + crow[r]];
  }

  float S[16];
#pragma unroll
  for (int r = 0; r < 16; ++r) S[r] = 0.f;
  float zacc = 0.f;

  const int ibase = ch * ICHUNK + w * IPW;
  const int frag_off = lc * D_ + half * 8;   // lane offset inside a 32x16 tile
  const size_t wstride = (size_t)J_ * C_ * D_;

  const f32x16 zeroacc = {0,0,0,0,0,0,0,0,0,0,0,0,0,0,0,0};

  if (READF32) {
    const float* wp0 = Wf + ((size_t)ibase * J_ + j) * (C_ * D_) + frag_off;
    for (int t = 0; t < IPW; ++t) {
      const int i = ibase + t;
      short8 ufrag = *(const short8*)(ut + (size_t)i * (B_ * D_) + frag_off);
      const float* wp = wp0 + (size_t)t * wstride;
      f32x4 w0 = __builtin_nontemporal_load((const f32x4*)wp);
      f32x4 w1 = __builtin_nontemporal_load((const f32x4*)(wp + 4));
      union { short8 v; bf16_t h[8]; } cv;
      cv.h[0] = __float2bfloat16(w0.x);
      cv.h[1] = __float2bfloat16(w0.y);
      cv.h[2] = __float2bfloat16(w0.z);
      cv.h[3] = __float2bfloat16(w0.w);
      cv.h[4] = __float2bfloat16(w1.x);
      cv.h[5] = __float2bfloat16(w1.y);
      cv.h[6] = __float2bfloat16(w1.z);
      cv.h[7] = __float2bfloat16(w1.w);
      short8 wfrag = cv.v;
      if (STOREB) *(short8*)(Wbo + (size_t)i * wstride + j * (C_ * D_) + frag_off) = wfrag;

      f32x16 acc = __builtin_amdgcn_mfma_f32_32x32x16_bf16(wfrag, ufrag, zeroacc, 0, 0, 0);
      if (UNIFORM) {
#pragma unroll
        for (int r = 0; r < 16; ++r) S[r] += acc[r];
      } else {
        float ph = 0.f;
#pragma unroll
        for (int r = 0; r < 16; ++r) ph = fmaf(Vreg[r], acc[r], ph);
        ph += __shfl_xor(ph, 32);
        float e = __expf(ph);
        zacc += e;
#pragma unroll
        for (int r = 0; r < 16; ++r) S[r] = fmaf(e, acc[r], S[r]);
      }
    }
  } else {
    const bf16_t* wp0 = Wb + ((size_t)ibase * J_ + j) * (C_ * D_) + frag_off;
    short8 wnext = *(const short8*)wp0;            // prefetch i=ibase
    for (int t = 0; t < IPW; ++t) {
      const int i = ibase + t;
      short8 wfrag = wnext;
      if (t + 1 < IPW)
        wnext = *(const short8*)(wp0 + (size_t)(t + 1) * wstride);
      short8 ufrag = *(const short8*)(ut + (size_t)i * (B_ * D_) + frag_off);

      f32x16 acc = __builtin_amdgcn_mfma_f32_32x32x16_bf16(wfrag, ufrag, zeroacc, 0, 0, 0);
      float ph = 0.f;
#pragma unroll
      for (int r = 0; r < 16; ++r) ph = fmaf(Vreg[r], acc[r], ph);
      ph += __shfl_xor(ph, 32);
      float e = __expf(ph);
      zacc += e;
#pragma unroll
      for (int r = 0; r < 16; ++r) S[r] = fmaf(e, acc[r], S[r]);
    }
  }

  // --- Block partial: transpose [c][b] -> [b][c] via padded LDS (stride 33,
  // bank = (lc + crow) % 32, conflict-free), write coalesced partials.
  __shared__ float S_lds[4 * 32 * 33];
  __shared__ float Z_lds[4 * 32];
#pragma unroll
  for (int r = 0; r < 16; ++r)
    S_lds[w * 1056 + lc * 33 + crow[r]] = S[r];
  if (!UNIFORM && !half)
    Z_lds[w * 32 + lc] = zacc;
  __syncthreads();

  const size_t pbase = (size_t)blockIdx.x * 1024;
  for (int e = tid; e < 1024; e += 256) {
    int b = e >> 5, c = e & 31;
    PS[pbase + e] = S_lds[b * 33 + c] + S_lds[1056 + b * 33 + c] +
                    S_lds[2112 + b * 33 + c] + S_lds[3168 + b * 33 + c];
  }
  if (!UNIFORM && tid < 32)
    PZ[(size_t)blockIdx.x * 32 + tid] =
        Z_lds[tid] + Z_lds[32 + tid] + Z_lds[64 + tid] + Z_lds[96 + tid];

  // --- Fused combine: last block for this j reduces all chunks, squashes,
  // updates V (or writes out). Release/acquire via threadfence + atomic.
  __threadfence();
  __shared__ int lastflag;
  if (tid == 0)
    lastflag = (atomicAdd(counter + j, 1u) == NCHUNK - 1);
  __syncthreads();
  if (!lastflag) return;
  __threadfence();

  for (int e = tid; e < 1024; e += 256) {
    int b = e >> 5, c = e & 31;
    float s = 0.f, zz = 0.f;
#pragma unroll
    for (int q = 0; q < NCHUNK; ++q) {
      s += PS[(size_t)(j * NCHUNK + q) * 1024 + e];
      if (!UNIFORM) zz += PZ[(j * NCHUNK + q) * 32 + b];
    }
    if (UNIFORM) zz = (float)N_;
    float sv = s / zz + 1e-7f;               // squash adds eps per-component
    float n = sv * sv;
    n += __shfl_xor(n, 1);
    n += __shfl_xor(n, 2);
    n += __shfl_xor(n, 4);
    n += __shfl_xor(n, 8);
    n += __shfl_xor(n, 16);
    float f = n / ((1.f + n) * sqrtf(n));
    float v = sv * f;
    int idx = (b * J_ + j) * C_ + c;
    if (last) out[idx] = v;
    else      Vout[idx] = first ? v : (V[idx] + v);
  }
}

extern "C" void kernel_launch(void* const* d_in, const int* in_sizes, int n_in,
                              void* d_out, int out_size, void* d_ws, size_t ws_size,
                              hipStream_t stream)
{
  const float* x  = (const float*)d_in[0];
  const float* Wf = (const float*)d_in[1];
  float* out = (float*)d_out;
  char* ws = (char*)d_ws;

  const size_t SZ_WB = (size_t)N_ * J_ * C_ * D_ * 2;      // 128 MB bf16 W cache
  const size_t SZ_UT = (size_t)N_ * B_ * D_ * 2;           // 2 MB
  const size_t SZ_V  = (size_t)B_ * J_ * C_ * 4;           // 256 KB
  const size_t SZ_PS = (size_t)J_ * NCHUNK * B_ * C_ * 4;  // 8 MB
  const size_t SZ_PZ = (size_t)J_ * NCHUNK * B_ * 4;       // 256 KB
  const size_t SZ_CN = (size_t)NPASS * J_ * 4;             // counters

  const bool big = ws_size >= SZ_WB + SZ_UT + SZ_V + SZ_PS + SZ_PZ + SZ_CN;
  size_t off = big ? SZ_WB : 0;
  bf16_t* Wb = (bf16_t*)ws;
  bf16_t* ut = (bf16_t*)(ws + off); off += SZ_UT;
  float*  V  = (float*)(ws + off);  off += SZ_V;
  float*  PS = (float*)(ws + off);  off += SZ_PS;
  float*  PZ = (float*)(ws + off);  off += SZ_PZ;
  unsigned* cnt = (unsigned*)(ws + off);

  prep_u_kernel<<<dim3((N_ * B_ * 4) / 256), dim3(256), 0, stream>>>(x, ut, cnt);

  dim3 gA(J_ * NCHUNK), blk(256);
  if (big) {
    pass_kernel<0><<<gA, blk, 0, stream>>>(Wf, nullptr, Wb, ut, nullptr,
                                           PS, PZ, V, out, cnt + 0 * J_, 1, 0);
    for (int it = 1; it < 5; ++it)
      pass_kernel<1><<<gA, blk, 0, stream>>>(nullptr, Wb, nullptr, ut, V,
                                             PS, PZ, V, out, cnt + it * J_,
                                             0, it == 4 ? 1 : 0);
  } else {
    pass_kernel<2><<<gA, blk, 0, stream>>>(Wf, nullptr, nullptr, ut, nullptr,
                                           PS, PZ, V, out, cnt + 0 * J_, 1, 0);
    for (int it = 1; it < 5; ++it)
      pass_kernel<3><<<gA, blk, 0, stream>>>(Wf, nullptr, nullptr, ut, V,
                                             PS, PZ, V, out, cnt + it * J_,
                                             0, it == 4 ? 1 : 0);
  }
}

// Round 4
// 540.725 us; speedup vs baseline: 3.7292x; 3.7292x over previous
//
#include <hip/hip_runtime.h>
#include <hip/hip_bf16.h>

#define B_ 32
#define N_ 2048
#define D_ 16
#define J_ 64
#define C_ 32
#define NCHUNK 32
#define ICHUNK 64          // N_/NCHUNK
#define IPW    16          // ICHUNK/4 waves

typedef __attribute__((ext_vector_type(8)))  short short8;
typedef __attribute__((ext_vector_type(4)))  short s16x4;
typedef __attribute__((ext_vector_type(16))) float f32x16;
typedef __attribute__((ext_vector_type(4)))  float f32x4;

using bf16_t = __hip_bfloat16;

// ---------------------------------------------------------------------------
// Prep: u (B,N,D) fp32 -> u_t (N,B,D) bf16, write-coalesced.
// ---------------------------------------------------------------------------
__global__ __launch_bounds__(256) void prep_u_kernel(const float* __restrict__ x,
                                                     bf16_t* __restrict__ ut) {
  int t  = blockIdx.x * 256 + threadIdx.x;   // t = (i*32 + b)*4 + d4
  int d4 = t & 3;
  int bi = t >> 2;
  int b  = bi & 31;
  int i  = bi >> 5;
  f32x4 xv = *(const f32x4*)(x + ((size_t)(b * N_ + i) * D_ + d4 * 4));
  union { s16x4 v; bf16_t h[4]; } o;
  o.h[0] = __float2bfloat16(xv.x);
  o.h[1] = __float2bfloat16(xv.y);
  o.h[2] = __float2bfloat16(xv.z);
  o.h[3] = __float2bfloat16(xv.w);
  *(s16x4*)(ut + (size_t)(i * B_ + b) * D_ + d4 * 4) = o.v;
}

// ---------------------------------------------------------------------------
// Routing pass. One block = (j, i-chunk of 64), 4 waves, 1 wave = 16 i's.
// NO cross-block fences/atomics (round-3 lesson: device-scope threadfence
// per block = L2 writeback storm on gfx950 -> 4x regression).
// mfma(wfrag, ufrag) -> acc[m=c][n=b]: col b = lane&31,
// row c = (r&3) + 4*(lane>>5) + 8*(r>>2)   (measured m74/m101)
// Logit dot over c is in-lane (16 fma) + one shfl_xor(32); 1 exp/lane/i.
// Wb uses CHUNK-MAJOR tile layout [(ch*J + j)*ICHUNK + ti] so each block's
// Wb region is one contiguous 128 KB (writes in MODE0, reads in MODE1).
// MODE 0: fp32 W in (nontemporal), store bf16 W, uniform weights (iter 0)
// MODE 1: bf16 W in, V-based logits (iters 1-4)
// MODE 2/3: fp32-W fallbacks (small ws), uniform / V-logits.
// ---------------------------------------------------------------------------
template<int MODE>
__global__ __launch_bounds__(256) void pass_kernel(
    const float*  __restrict__ Wf,
    const bf16_t* __restrict__ Wb,
    bf16_t*       __restrict__ Wbo,
    const bf16_t* __restrict__ ut,
    const float*  __restrict__ V,
    float*        __restrict__ PS,
    float*        __restrict__ PZ)
{
  constexpr bool UNIFORM = (MODE == 0 || MODE == 2);
  constexpr bool READF32 = (MODE != 1);
  constexpr bool STOREB  = (MODE == 0);

  const int tid  = threadIdx.x;
  const int w    = tid >> 6;
  const int lane = tid & 63;
  const int half = lane >> 5;
  const int lc   = lane & 31;          // = b (acc col); A/B-frag free index

  const int j  = blockIdx.x / NCHUNK;
  const int ch = blockIdx.x % NCHUNK;

  int crow[16];                        // acc row (= c) per accumulator reg
#pragma unroll
  for (int r = 0; r < 16; ++r) crow[r] = (r & 3) + 4 * half + 8 * (r >> 2);

  float Vreg[16];
  if (!UNIFORM) {
#pragma unroll
    for (int r = 0; r < 16; ++r) Vreg[r] = V[(lc * J_ + j) * C_ + crow[r]];
  }

  float S[16];
#pragma unroll
  for (int r = 0; r < 16; ++r) S[r] = 0.f;
  float zacc = 0.f;

  const int ibase = ch * ICHUNK + w * IPW;       // global i for this wave
  const int frag_off = lc * D_ + half * 8;       // lane offset in a 32x16 tile
  const size_t wstride  = (size_t)J_ * C_ * D_;  // Wf tile stride over i
  // chunk-major Wb: tiles for this block start at (ch*J + j)*ICHUNK,
  // this wave's 16 tiles start at +w*IPW, stride C_*D_ (contiguous).
  const size_t wbbase = ((size_t)(ch * J_ + j) * ICHUNK + w * IPW) * (C_ * D_);

  const f32x16 zeroacc = {0,0,0,0,0,0,0,0,0,0,0,0,0,0,0,0};

  if (READF32) {
    const float* wp0 = Wf + ((size_t)ibase * J_ + j) * (C_ * D_) + frag_off;
    for (int t = 0; t < IPW; ++t) {
      const int i = ibase + t;
      short8 ufrag = *(const short8*)(ut + (size_t)i * (B_ * D_) + frag_off);
      const float* wp = wp0 + (size_t)t * wstride;
      f32x4 w0 = __builtin_nontemporal_load((const f32x4*)wp);
      f32x4 w1 = __builtin_nontemporal_load((const f32x4*)(wp + 4));
      union { short8 v; bf16_t h[8]; } cv;
      cv.h[0] = __float2bfloat16(w0.x);
      cv.h[1] = __float2bfloat16(w0.y);
      cv.h[2] = __float2bfloat16(w0.z);
      cv.h[3] = __float2bfloat16(w0.w);
      cv.h[4] = __float2bfloat16(w1.x);
      cv.h[5] = __float2bfloat16(w1.y);
      cv.h[6] = __float2bfloat16(w1.z);
      cv.h[7] = __float2bfloat16(w1.w);
      short8 wfrag = cv.v;
      if (STOREB)
        *(short8*)(Wbo + wbbase + (size_t)t * (C_ * D_) + frag_off) = wfrag;

      f32x16 acc = __builtin_amdgcn_mfma_f32_32x32x16_bf16(wfrag, ufrag, zeroacc, 0, 0, 0);
      if (UNIFORM) {
#pragma unroll
        for (int r = 0; r < 16; ++r) S[r] += acc[r];
      } else {
        float ph = 0.f;
#pragma unroll
        for (int r = 0; r < 16; ++r) ph = fmaf(Vreg[r], acc[r], ph);
        ph += __shfl_xor(ph, 32);
        float e = __expf(ph);
        zacc += e;
#pragma unroll
        for (int r = 0; r < 16; ++r) S[r] = fmaf(e, acc[r], S[r]);
      }
    }
  } else {
    const bf16_t* wp0 = Wb + wbbase + frag_off;
    short8 wnext = *(const short8*)wp0;            // prefetch t=0
    for (int t = 0; t < IPW; ++t) {
      const int i = ibase + t;
      short8 wfrag = wnext;
      if (t + 1 < IPW)
        wnext = *(const short8*)(wp0 + (size_t)(t + 1) * (C_ * D_));
      short8 ufrag = *(const short8*)(ut + (size_t)i * (B_ * D_) + frag_off);

      f32x16 acc = __builtin_amdgcn_mfma_f32_32x32x16_bf16(wfrag, ufrag, zeroacc, 0, 0, 0);
      float ph = 0.f;
#pragma unroll
      for (int r = 0; r < 16; ++r) ph = fmaf(Vreg[r], acc[r], ph);
      ph += __shfl_xor(ph, 32);
      float e = __expf(ph);
      zacc += e;
#pragma unroll
      for (int r = 0; r < 16; ++r) S[r] = fmaf(e, acc[r], S[r]);
    }
  }

  // Epilogue: transpose [c][b] -> [b][c] through padded LDS (stride 33:
  // bank = (lc + crow) % 32, conflict-free), then coalesced PS writes.
  __shared__ float S_lds[4 * 32 * 33];
  __shared__ float Z_lds[4 * 32];
#pragma unroll
  for (int r = 0; r < 16; ++r)
    S_lds[w * 1056 + lc * 33 + crow[r]] = S[r];
  if (!half)
    Z_lds[w * 32 + lc] = UNIFORM ? (float)IPW : zacc;
  __syncthreads();

  const size_t pbase = (size_t)blockIdx.x * 1024;
  for (int e = tid; e < 1024; e += 256) {
    int b = e >> 5, c = e & 31;
    PS[pbase + e] = S_lds[b * 33 + c] + S_lds[1056 + b * 33 + c] +
                    S_lds[2112 + b * 33 + c] + S_lds[3168 + b * 33 + c];
  }
  if (tid < 32)
    PZ[(size_t)blockIdx.x * 32 + tid] =
        Z_lds[tid] + Z_lds[32 + tid] + Z_lds[64 + tid] + Z_lds[96 + tid];
}

// ---------------------------------------------------------------------------
// Combine chunks -> s, squash -> v, V += v, final iter writes output.
// ---------------------------------------------------------------------------
__global__ __launch_bounds__(256) void combine_kernel(
    const float* __restrict__ PS, const float* __restrict__ PZ,
    float* __restrict__ V, float* __restrict__ out, int first, int last)
{
  int t  = blockIdx.x * 256 + threadIdx.x;  // ((b*J + j)*32 + c)
  int c  = t & 31;
  int bj = t >> 5;
  int b  = bj >> 6;
  int j  = bj & 63;
  float s = 0.f, zz = 0.f;
#pragma unroll
  for (int ch = 0; ch < NCHUNK; ++ch) {
    s  += PS[(size_t)(j * NCHUNK + ch) * 1024 + b * 32 + c];
    zz += PZ[(j * NCHUNK + ch) * 32 + b];
  }
  float sv = s / zz + 1e-7f;                // squash adds eps per-component
  float n = sv * sv;
  n += __shfl_xor(n, 1);
  n += __shfl_xor(n, 2);
  n += __shfl_xor(n, 4);
  n += __shfl_xor(n, 8);
  n += __shfl_xor(n, 16);
  float f = n / ((1.f + n) * sqrtf(n));
  float v = sv * f;
  float Vn = first ? v : (V[t] + v);
  V[t] = Vn;
  if (last) out[t] = v;
}

extern "C" void kernel_launch(void* const* d_in, const int* in_sizes, int n_in,
                              void* d_out, int out_size, void* d_ws, size_t ws_size,
                              hipStream_t stream)
{
  const float* x  = (const float*)d_in[0];
  const float* Wf = (const float*)d_in[1];
  float* out = (float*)d_out;
  char* ws = (char*)d_ws;

  const size_t SZ_WB = (size_t)N_ * J_ * C_ * D_ * 2;      // 128 MB bf16 W cache
  const size_t SZ_UT = (size_t)N_ * B_ * D_ * 2;           // 2 MB
  const size_t SZ_V  = (size_t)B_ * J_ * C_ * 4;           // 256 KB
  const size_t SZ_PS = (size_t)J_ * NCHUNK * B_ * C_ * 4;  // 8 MB
  const size_t SZ_PZ = (size_t)J_ * NCHUNK * B_ * 4;       // 256 KB

  const bool big = ws_size >= SZ_WB + SZ_UT + SZ_V + SZ_PS + SZ_PZ;
  size_t off = big ? SZ_WB : 0;
  bf16_t* Wb = (bf16_t*)ws;
  bf16_t* ut = (bf16_t*)(ws + off); off += SZ_UT;
  float*  V  = (float*)(ws + off);  off += SZ_V;
  float*  PS = (float*)(ws + off);  off += SZ_PS;
  float*  PZ = (float*)(ws + off);

  prep_u_kernel<<<dim3((N_ * B_ * 4) / 256), dim3(256), 0, stream>>>(x, ut);

  dim3 gA(J_ * NCHUNK), blk(256), gB((B_ * J_ * C_) / 256);
  if (big) {
    pass_kernel<0><<<gA, blk, 0, stream>>>(Wf, nullptr, Wb, ut, nullptr, PS, PZ);
    combine_kernel<<<gB, blk, 0, stream>>>(PS, PZ, V, out, 1, 0);
    for (int it = 1; it < 5; ++it) {
      pass_kernel<1><<<gA, blk, 0, stream>>>(nullptr, Wb, nullptr, ut, V, PS, PZ);
      combine_kernel<<<gB, blk, 0, stream>>>(PS, PZ, V, out, 0, it == 4 ? 1 : 0);
    }
  } else {
    pass_kernel<2><<<gA, blk, 0, stream>>>(Wf, nullptr, nullptr, ut, nullptr, PS, PZ);
    combine_kernel<<<gB, blk, 0, stream>>>(PS, PZ, V, out, 1, 0);
    for (int it = 1; it < 5; ++it) {
      pass_kernel<3><<<gA, blk, 0, stream>>>(Wf, nullptr, nullptr, ut, V, PS, PZ);
      combine_kernel<<<gB, blk, 0, stream>>>(PS, PZ, V, out, 0, it == 4 ? 1 : 0);
    }
  }
}